// Round 7
// baseline (126.887 us; speedup 1.0000x reference)
//
#include <hip/hip_runtime.h>
#include <hip/hip_bf16.h>

// EdgeConv forward via MFMA. Round 7: SINGLE KERNEL, no prep pass.
//
// out[i] = max_j relu(W @ concat(x_i, x_j - x_i) + b), DEG=16 contiguous/node.
// Split W=[W1|W2]: msg = base + x_j.W2^T, base = b + x_i.(W1-W2)^T.
//
// Timing model (R5 differential + R6): dur ~= 75us serial harness floor
// (256MB ws-poison fill 46.5us + out-poison + input restores + gaps)
//   + prep ~5us + edge ~18us.  R7 deletes prep entirely: gather fp32 x
// directly (205 MB vs 102 MB bf16) and convert to bf16 fragments in-register
// (__float22bfloat162_rn -> HW pack-cvt on gfx950); W fragments built
// per-wave from fp32 W (32KB, L1/L2-resident, ~100 VALU/wave).
// Differential read: if edge grows >> 2us, gather is service-bound and R6
// was already at the memory-system floor.
//
// Fragment layouts (m89/m91-verified):
//   A[m=lane&15][k=(lane>>4)*8+j] -> features row*C + ks*32 + quad*8 ..+8
//   B[k=(lane>>4)*8+j][n=lane&15],  D: col=lane&15, row=(lane>>4)*4+reg

#define DEG 16
#define C 64
#define NPW 8    // nodes per wave
#define WPB 4    // waves per block
#define PIPE 4   // gather software-pipeline depth (fp32 stage = 64 VGPRs)

typedef __attribute__((ext_vector_type(8))) short s16x8;  // 8 bf16 = 4 VGPRs
typedef __attribute__((ext_vector_type(4))) float f32x4;  // MFMA C/D

// pack two fp32 -> bf16x2 (RNE; HW v_cvt_pk_bf16_f32 on gfx950)
__device__ __forceinline__ unsigned pk2(float lo, float hi) {
    __hip_bfloat162 h = __float22bfloat162_rn(make_float2(lo, hi));
    union { __hip_bfloat162 h; unsigned u; } c; c.h = h;
    return c.u;  // lo in bits [15:0], hi in [31:16]
}

// 8 fp32 (two f32x4) -> one A/B fragment (8 bf16)
__device__ __forceinline__ s16x8 cvt_frag(f32x4 a, f32x4 b) {
    union { unsigned u[4]; s16x8 v; } r;
    r.u[0] = pk2(a[0], a[1]); r.u[1] = pk2(a[2], a[3]);
    r.u[2] = pk2(b[0], b[1]); r.u[3] = pk2(b[2], b[3]);
    return r.v;
}

// Load the 16 fp32 features backing both A fragments of one row:
// [quad*8 .. +8) and [32+quad*8 .. +8)
__device__ __forceinline__ void load4(f32x4* d, const float* __restrict__ x,
                                      int row, int quad) {
    const float* p = x + row * C + quad * 8;
    d[0] = *(const f32x4*)p;
    d[1] = *(const f32x4*)(p + 4);
    d[2] = *(const f32x4*)(p + 32);
    d[3] = *(const f32x4*)(p + 36);
}

__global__ __launch_bounds__(256, 3) void edgeconv_fused(
    const float* __restrict__ x,     // [N,64] fp32
    const int*   __restrict__ src,   // [E] edge sources
    const float* __restrict__ W,     // [64,128] row-major
    const float* __restrict__ bias,  // [64]
    float*       __restrict__ out,   // [N,64]
    int n_groups)
{
    const int lane = threadIdx.x & 63;
    const int wave = threadIdx.x >> 6;
    const int col  = lane & 15;
    const int quad = lane >> 4;
    int group = blockIdx.x * WPB + wave;
    if (group >= n_groups) group = n_groups - 1;  // dup work, identical writes
    const int node0 = group * NPW;

    // ---- 1. edge indices (head of the longest dependent chain) ----
    int idx[NPW];
    #pragma unroll
    for (int n = 0; n < NPW; ++n)
        idx[n] = src[node0 * DEG + n * DEG + col];  // lane's A-row = edge col

    // ---- 2. prologue: issue gather pipeline (PIPE nodes, fp32) ----
    f32x4 xf[PIPE][4];
    #pragma unroll
    for (int p = 0; p < PIPE; ++p)
        load4(xf[p], x, idx[p], quad);

    // ---- 3. W fragments built in-wave (W is 32KB, L1/L2-hot) ----
    s16x8 bd[4][2], b2[4][2];
    #pragma unroll
    for (int nt = 0; nt < 4; ++nt) {
        const float* wrow = W + (nt * 16 + col) * (2 * C);
        #pragma unroll
        for (int ks = 0; ks < 2; ++ks) {
            const int k0 = ks * 32 + quad * 8;
            f32x4 w1a = *(const f32x4*)(wrow + k0);
            f32x4 w1b = *(const f32x4*)(wrow + k0 + 4);
            f32x4 w2a = *(const f32x4*)(wrow + C + k0);
            f32x4 w2b = *(const f32x4*)(wrow + C + k0 + 4);
            b2[nt][ks] = cvt_frag(w2a, w2b);
            f32x4 da, db;
            #pragma unroll
            for (int j = 0; j < 4; ++j) { da[j] = w1a[j] - w2a[j]; db[j] = w1b[j] - w2b[j]; }
            bd[nt][ks] = cvt_frag(da, db);
        }
    }

    // ---- 4. stage 1: base = bias + XI @ (W1-W2)^T ----
    // A rows 0..7 = the wave's 8 nodes (rows 8..15 dup via col&7: harmless).
    f32x4 xif[4];
    load4(xif, x, node0 + (col & 7), quad);
    s16x8 xi0 = cvt_frag(xif[0], xif[1]);
    s16x8 xi1 = cvt_frag(xif[2], xif[3]);
    f32x4 baseD[4];
    #pragma unroll
    for (int nt = 0; nt < 4; ++nt) {
        float bv = bias[nt * 16 + col];
        baseD[nt] = (f32x4){bv, bv, bv, bv};
    }
    #pragma unroll
    for (int nt = 0; nt < 4; ++nt) {
        baseD[nt] = __builtin_amdgcn_mfma_f32_16x16x32_bf16(xi0, bd[nt][0], baseD[nt], 0, 0, 0);
        baseD[nt] = __builtin_amdgcn_mfma_f32_16x16x32_bf16(xi1, bd[nt][1], baseD[nt], 0, 0, 0);
    }
    // base[node n][nt*16+c]: lane ((n>>2)<<4)|c, reg n&3.

    // ---- 5. pipelined per-node: convert, MSG = base + XJ@W2^T, max, store ----
    #pragma unroll
    for (int n = 0; n < NPW; ++n) {
        s16x8 fa0 = cvt_frag(xf[n % PIPE][0], xf[n % PIPE][1]);
        s16x8 fa1 = cvt_frag(xf[n % PIPE][2], xf[n % PIPE][3]);
        if (n + PIPE < NPW)
            load4(xf[n % PIPE], x, idx[n + PIPE], quad);  // refill slot

        const int slane = ((n >> 2) << 4) | col;
        f32x4 acc[4];
        #pragma unroll
        for (int nt = 0; nt < 4; ++nt) {
            float bb = __shfl(baseD[nt][n & 3], slane);  // base[n][nt*16+col]
            acc[nt] = (f32x4){bb, bb, bb, bb};
        }
        #pragma unroll
        for (int nt = 0; nt < 4; ++nt) {
            acc[nt] = __builtin_amdgcn_mfma_f32_16x16x32_bf16(fa0, b2[nt][0], acc[nt], 0, 0, 0);
            acc[nt] = __builtin_amdgcn_mfma_f32_16x16x32_bf16(fa1, b2[nt][1], acc[nt], 0, 0, 0);
        }
        // max over edges (rows): 4 regs in-lane, then cross-quad shfl_xor.
        float m[4];
        #pragma unroll
        for (int nt = 0; nt < 4; ++nt) {
            float t = fmaxf(fmaxf(acc[nt][0], acc[nt][1]),
                            fmaxf(acc[nt][2], acc[nt][3]));
            t = fmaxf(t, __shfl_xor(t, 16));
            t = fmaxf(t, __shfl_xor(t, 32));
            m[nt] = t;
        }
        float r = quad == 0 ? m[0] : quad == 1 ? m[1] : quad == 2 ? m[2] : m[3];
        r = fmaxf(r, 0.0f);  // relu (monotone: fold after max)
        out[(node0 + n) * C + lane] = r;  // coalesced 256B/node
    }
}

extern "C" void kernel_launch(void* const* d_in, const int* in_sizes, int n_in,
                              void* d_out, int out_size, void* d_ws, size_t ws_size,
                              hipStream_t stream) {
    const float* x    = (const float*)d_in[0];
    const int*   src  = (const int*)  d_in[1];   // row 0 of edge_index
    const float* W    = (const float*)d_in[3];
    const float* b    = (const float*)d_in[4];
    float*       out  = (float*)d_out;

    const int n_nodes  = in_sizes[0] / C;                // 50000
    const int n_groups = (n_nodes + NPW - 1) / NPW;      // 6250
    const int grid     = (n_groups + WPB - 1) / WPB;     // 1563

    edgeconv_fused<<<grid, 256, 0, stream>>>(x, src, W, b, out, n_groups);
}

// Round 8
// 105.493 us; speedup vs baseline: 1.2028x; 1.2028x over previous
//
#include <hip/hip_runtime.h>
#include <hip/hip_bf16.h>

// EdgeConv forward, Round 8: FACTORED.
//   out[i] = relu(base_i + max_{j in N(i)} y_j)      (elementwise, DEG=16)
//   y      = X @ W2^T                (bf16, in ws)
//   base   = bias + X @ (W1-W2)^T    (fp32, in ws)
// Valid because max over edges is elementwise and base_i is edge-invariant;
// relu folds outside the max (monotone; every node has exactly 16 edges).
//
// R7 measurement: gather phase is latency-bound random-line service
// (80 MB L2-miss @ 1.6 TB/s, occupancy 24%). Factoring deletes all MFMA/W
// state from the gather kernel -> ~40 VGPR, launch_bounds(256,8), 16
// coalesced 128B line-loads in flight per wave: latency-hiding via raw
// concurrency. Dense GEMM phase is a tiny streaming MFMA kernel.
//
// Fragment layouts (m89/m91-verified):
//   A[m=lane&15][k=(lane>>4)*8+j], B[k=(lane>>4)*8+j][n=lane&15],
//   D: col=lane&15, row=(lane>>4)*4+reg

#define DEG 16
#define C 64
#define WPB 4

typedef __attribute__((ext_vector_type(8))) short s16x8;
typedef __attribute__((ext_vector_type(4))) float f32x4;

__device__ __forceinline__ unsigned pk2(float lo, float hi) {
    __hip_bfloat162 h = __float22bfloat162_rn(make_float2(lo, hi));
    union { __hip_bfloat162 h; unsigned u; } c; c.h = h;
    return c.u;
}
__device__ __forceinline__ s16x8 cvt_frag(f32x4 a, f32x4 b) {
    union { unsigned u[4]; s16x8 v; } r;
    r.u[0] = pk2(a[0], a[1]); r.u[1] = pk2(a[2], a[3]);
    r.u[2] = pk2(b[0], b[1]); r.u[3] = pk2(b[2], b[3]);
    return r.v;
}
__device__ __forceinline__ float bf2f(unsigned short u) {
    union { unsigned u; float f; } c; c.u = ((unsigned)u) << 16;
    return c.f;
}

// ---- kernel 1: Y = X@W2^T (bf16), base = bias + X@(W1-W2)^T (fp32) ----
// One wave per 16 rows. 16 MFMAs/wave. 3125 waves.
__global__ __launch_bounds__(256) void dense_yb(
    const float* __restrict__ x,     // [N,64]
    const float* __restrict__ W,     // [64,128]
    const float* __restrict__ bias,  // [64]
    unsigned short* __restrict__ Y,  // [N,64] bf16 out
    float* __restrict__ B,           // [N,64] fp32 out
    int n_groups, int n_nodes)
{
    const int lane = threadIdx.x & 63;
    const int wave = threadIdx.x >> 6;
    const int col  = lane & 15;
    const int quad = lane >> 4;
    int group = blockIdx.x * WPB + wave;
    if (group >= n_groups) group = n_groups - 1;  // dup work, identical writes
    const int node0 = group * 16;

    // W fragments (in-wave build; W is 32KB, L1/L2-hot)
    s16x8 bd[4][2], b2[4][2];
    #pragma unroll
    for (int nt = 0; nt < 4; ++nt) {
        const float* wrow = W + (nt * 16 + col) * (2 * C);
        #pragma unroll
        for (int ks = 0; ks < 2; ++ks) {
            const int k0 = ks * 32 + quad * 8;
            f32x4 w1a = *(const f32x4*)(wrow + k0);
            f32x4 w1b = *(const f32x4*)(wrow + k0 + 4);
            f32x4 w2a = *(const f32x4*)(wrow + C + k0);
            f32x4 w2b = *(const f32x4*)(wrow + C + k0 + 4);
            b2[nt][ks] = cvt_frag(w2a, w2b);
            f32x4 da, db;
            #pragma unroll
            for (int j = 0; j < 4; ++j) { da[j] = w1a[j] - w2a[j]; db[j] = w1b[j] - w2b[j]; }
            bd[nt][ks] = cvt_frag(da, db);
        }
    }

    // A fragments: rows node0..node0+15 (clamped at tail)
    int arow = node0 + col;
    if (arow >= n_nodes) arow = n_nodes - 1;
    const float* xp = x + (size_t)arow * C + quad * 8;
    s16x8 xi0 = cvt_frag(*(const f32x4*)xp, *(const f32x4*)(xp + 4));
    s16x8 xi1 = cvt_frag(*(const f32x4*)(xp + 32), *(const f32x4*)(xp + 36));

    f32x4 yD[4], bD[4];
    #pragma unroll
    for (int nt = 0; nt < 4; ++nt) {
        float bv = bias[nt * 16 + col];
        bD[nt] = (f32x4){bv, bv, bv, bv};
        yD[nt] = (f32x4){0.f, 0.f, 0.f, 0.f};
    }
    #pragma unroll
    for (int nt = 0; nt < 4; ++nt) {
        yD[nt] = __builtin_amdgcn_mfma_f32_16x16x32_bf16(xi0, b2[nt][0], yD[nt], 0, 0, 0);
        yD[nt] = __builtin_amdgcn_mfma_f32_16x16x32_bf16(xi1, b2[nt][1], yD[nt], 0, 0, 0);
        bD[nt] = __builtin_amdgcn_mfma_f32_16x16x32_bf16(xi0, bd[nt][0], bD[nt], 0, 0, 0);
        bD[nt] = __builtin_amdgcn_mfma_f32_16x16x32_bf16(xi1, bd[nt][1], bD[nt], 0, 0, 0);
    }

    // D layout: row = quad*4 + r, col = nt*16 + col
    #pragma unroll
    for (int r = 0; r < 4; ++r) {
        int row = node0 + quad * 4 + r;
        if (row >= n_nodes) row = n_nodes - 1;  // dup store, same value
        #pragma unroll
        for (int nt = 0; nt < 4; ++nt) {
            union { unsigned short s[1]; } dummy;
            (void)dummy;
            unsigned pk = pk2(yD[nt][r], 0.f);
            Y[(size_t)row * C + nt * 16 + col] = (unsigned short)(pk & 0xFFFF);
            B[(size_t)row * C + nt * 16 + col] = bD[nt][r];
        }
    }
}

// ---- kernel 2: out[i] = relu(B_i + max_e Y[src[i*16+e]]) ----
// One wave per node; lane = channel. 16 coalesced 128B line-loads, all
// independent, issued before the reduction. Tiny VGPR -> high occupancy.
__global__ __launch_bounds__(256, 8) void gathermax(
    const unsigned short* __restrict__ Y,  // [N,64] bf16
    const float* __restrict__ B,           // [N,64] fp32
    const int* __restrict__ src,           // [E]
    float* __restrict__ out,               // [N,64]
    int n_nodes)
{
    const int lane = threadIdx.x & 63;
    const int wave = threadIdx.x >> 6;
    int i = blockIdx.x * WPB + wave;
    if (i >= n_nodes) i = n_nodes - 1;  // dup work, identical writes

    // 16 source indices for this node, one per lane 0..15
    int jreg = 0;
    if (lane < DEG) jreg = src[i * DEG + lane];

    // base (independent, issued early)
    float bs = B[(size_t)i * C + lane];

    // broadcast indices, issue all 16 gathers
    unsigned short v[DEG];
    #pragma unroll
    for (int e = 0; e < DEG; ++e) {
        int j = __shfl(jreg, e);
        v[e] = Y[(size_t)j * C + lane];  // 64 lanes x 2B = one 128B line
    }

    float m = bf2f(v[0]);
    #pragma unroll
    for (int e = 1; e < DEG; ++e) m = fmaxf(m, bf2f(v[e]));

    out[(size_t)i * C + lane] = fmaxf(bs + m, 0.0f);
}

// ---- fallback (ws too small): R3-proven fused kernel ----
__global__ __launch_bounds__(256, 2) void edgeconv_fallback(
    const float* __restrict__ x, const int* __restrict__ src,
    const float* __restrict__ W, const float* __restrict__ bias,
    float* __restrict__ out, int n_groups)
{
    const int lane = threadIdx.x & 63, wave = threadIdx.x >> 6;
    const int col = lane & 15, quad = lane >> 4;
    int group = blockIdx.x * WPB + wave;
    if (group >= n_groups) group = n_groups - 1;

    auto frag = [&](int row, int koff) {
        const float* p = x + row * C + koff;
        return cvt_frag(*(const f32x4*)p, *(const f32x4*)(p + 4));
    };

    s16x8 b2[4][2];
    f32x4 baseD[4];
    {
        s16x8 bd[4][2];
        #pragma unroll
        for (int nt = 0; nt < 4; ++nt) {
            const float* wrow = W + (nt * 16 + col) * (2 * C);
            #pragma unroll
            for (int ks = 0; ks < 2; ++ks) {
                const int k0 = ks * 32 + quad * 8;
                f32x4 w1a = *(const f32x4*)(wrow + k0);
                f32x4 w1b = *(const f32x4*)(wrow + k0 + 4);
                f32x4 w2a = *(const f32x4*)(wrow + C + k0);
                f32x4 w2b = *(const f32x4*)(wrow + C + k0 + 4);
                b2[nt][ks] = cvt_frag(w2a, w2b);
                f32x4 da, db;
                #pragma unroll
                for (int j = 0; j < 4; ++j) { da[j] = w1a[j] - w2a[j]; db[j] = w1b[j] - w2b[j]; }
                bd[nt][ks] = cvt_frag(da, db);
            }
        }
        #pragma unroll
        for (int nt = 0; nt < 4; ++nt) {
            float bv = bias[nt * 16 + col];
            baseD[nt] = (f32x4){bv, bv, bv, bv};
        }
        const int nrow = group * 16 + col;
        s16x8 xi0 = frag(nrow, quad * 8), xi1 = frag(nrow, 32 + quad * 8);
        #pragma unroll
        for (int nt = 0; nt < 4; ++nt) {
            baseD[nt] = __builtin_amdgcn_mfma_f32_16x16x32_bf16(xi0, bd[nt][0], baseD[nt], 0, 0, 0);
            baseD[nt] = __builtin_amdgcn_mfma_f32_16x16x32_bf16(xi1, bd[nt][1], baseD[nt], 0, 0, 0);
        }
    }
    int idx[16];
    #pragma unroll
    for (int n = 0; n < 16; ++n) idx[n] = src[group * 256 + n * DEG + col];
    s16x8 xa[3][2];
    #pragma unroll
    for (int p = 0; p < 2; ++p) {
        xa[p][0] = frag(idx[p], quad * 8); xa[p][1] = frag(idx[p], 32 + quad * 8);
    }
    #pragma unroll
    for (int n = 0; n < 16; ++n) {
        if (n + 2 < 16) {
            xa[(n + 2) % 3][0] = frag(idx[n + 2], quad * 8);
            xa[(n + 2) % 3][1] = frag(idx[n + 2], 32 + quad * 8);
        }
        const int slane = ((n >> 2) << 4) | col;
        f32x4 acc[4];
        #pragma unroll
        for (int nt = 0; nt < 4; ++nt) {
            float bb = __shfl(baseD[nt][n & 3], slane);
            acc[nt] = (f32x4){bb, bb, bb, bb};
        }
        #pragma unroll
        for (int nt = 0; nt < 4; ++nt) {
            acc[nt] = __builtin_amdgcn_mfma_f32_16x16x32_bf16(xa[n % 3][0], b2[nt][0], acc[nt], 0, 0, 0);
            acc[nt] = __builtin_amdgcn_mfma_f32_16x16x32_bf16(xa[n % 3][1], b2[nt][1], acc[nt], 0, 0, 0);
        }
        float m[4];
        #pragma unroll
        for (int nt = 0; nt < 4; ++nt) {
            float t = fmaxf(fmaxf(acc[nt][0], acc[nt][1]),
                            fmaxf(acc[nt][2], acc[nt][3]));
            t = fmaxf(t, __shfl_xor(t, 16));
            t = fmaxf(t, __shfl_xor(t, 32));
            m[nt] = t;
        }
        float r = quad == 0 ? m[0] : quad == 1 ? m[1] : quad == 2 ? m[2] : m[3];
        out[(group * 16 + n) * C + lane] = fmaxf(r, 0.0f);
    }
}

extern "C" void kernel_launch(void* const* d_in, const int* in_sizes, int n_in,
                              void* d_out, int out_size, void* d_ws, size_t ws_size,
                              hipStream_t stream) {
    const float* x    = (const float*)d_in[0];
    const int*   src  = (const int*)  d_in[1];   // row 0 of edge_index
    const float* W    = (const float*)d_in[3];
    const float* b    = (const float*)d_in[4];
    float*       out  = (float*)d_out;

    const int n_nodes = in_sizes[0] / C;  // 50000

    // ws: [ Y bf16 : N*C ushort ][ B fp32 : N*C float ]  (Y first, 16B-aligned)
    const size_t y_bytes = (size_t)n_nodes * C * sizeof(unsigned short);
    const size_t b_bytes = (size_t)n_nodes * C * sizeof(float);

    if (ws_size >= y_bytes + b_bytes) {
        unsigned short* Y = (unsigned short*)d_ws;
        float* B = (float*)((char*)d_ws + y_bytes);
        const int n_groups = (n_nodes + 15) / 16;            // 3125
        dense_yb<<<(n_groups + WPB - 1) / WPB, 256, 0, stream>>>(
            x, W, b, Y, B, n_groups, n_nodes);
        gathermax<<<(n_nodes + WPB - 1) / WPB, 256, 0, stream>>>(
            Y, B, src, out, n_nodes);
    } else {
        const int n_groups = (n_nodes + 15) / 16;
        edgeconv_fallback<<<(n_groups + WPB - 1) / WPB, 256, 0, stream>>>(
            x, src, W, b, out, n_groups);
    }
}